// Round 7
// baseline (455.096 us; speedup 1.0000x reference)
//
#include <hip/hip_runtime.h>

// LSTM cell, B=131072, IN=H=128, fp32 in/out.
// R9: abandon persistent branch (R6-R8 all spill ~160 MiB scratch regardless of
// launch-bound attributes; VGPR pinned at 64 by backend, uncontrollable).
// Back to R3 structure (best clean: 126.8us) minus its biggest serial cost:
// the A staging path (f2bf + LDS round trip + 2 barriers + barrier-gated Bp
// stream). New: prep_xh pre-converts x|h to row-major bf16 XH[131072][256]
// (64 MB workspace). Main kernel loads A-fragments DIRECTLY from XH per
// (mi,kc): 16B/lane at the exact MFMA layout; all 8 waves share the same
// 32 KB A-tile -> L1-resident after first wave. Bp loads are nontemporal so
// the 256KB weight stream doesn't evict A from L1. Block becomes:
// c_prev load+park -> barrier-free GEMM -> bar -> epilogue -> bar -> stores.
// 2 barriers (was 4), no staging VALU, GEMM issues from cycle 0.
// Registers ~ R3's proven 64 arch + 64 AGPR at (512,4).

#define B_ROWS 131072
#define HDIM 128
#define BM 64
#define LDT 132   // padded LDS tile row stride (floats); 2-way bank aliasing only

typedef __attribute__((ext_vector_type(4))) float f32x4;
typedef __attribute__((ext_vector_type(8))) short s16x8;

__device__ inline unsigned short f2bf(float f) {
    unsigned int u = __float_as_uint(f);
    u += 0x7fffu + ((u >> 16) & 1u);   // RNE (inputs finite)
    return (unsigned short)(u >> 16);
}

__device__ inline float frcp(float x) { return __builtin_amdgcn_rcpf(x); }
__device__ inline float fsigmoid(float x) { return frcp(1.0f + __expf(-x)); }
__device__ inline float ftanh(float x) { return 1.0f - 2.0f * frcp(__expf(2.0f * x) + 1.0f); }

// Bp layout (ushort idx): (((w*8 + kc)*4 + ni)*512) + t16*32 + q*8 + e
__global__ void prep_weights(const float* __restrict__ Wi, const float* __restrict__ Ui,
                             const float* __restrict__ Wf, const float* __restrict__ Uf,
                             const float* __restrict__ Wg, const float* __restrict__ Ug,
                             const float* __restrict__ Wo, const float* __restrict__ Uo,
                             unsigned short* __restrict__ Bp) {
    int idx = blockIdx.x * 256 + threadIdx.x;   // 0..131071
    int e   = idx & 7;
    int q   = (idx >> 3) & 3;
    int t16 = (idx >> 5) & 15;
    int ni  = (idx >> 9) & 3;
    int kc  = (idx >> 11) & 7;
    int w   = idx >> 14;
    int j = w * 16 + t16;
    int k = kc * 32 + q * 8 + e;
    const float* Wp = ni == 0 ? Wi : ni == 1 ? Wf : ni == 2 ? Wg : Wo;
    const float* Up = ni == 0 ? Ui : ni == 1 ? Uf : ni == 2 ? Ug : Uo;
    float v = (k < 128) ? Wp[k * HDIM + j] : Up[(k - 128) * HDIM + j];
    Bp[idx] = f2bf(v);
}

// XH[r][k] (bf16, row-major 256 wide) = k<128 ? x[r][k] : h_prev[r][k-128]
__global__ __launch_bounds__(256) void prep_xh(const float* __restrict__ x,
                                               const float* __restrict__ h_prev,
                                               unsigned short* __restrict__ XH) {
    int idx = blockIdx.x * 256 + threadIdx.x;   // 0..4194303, one 8-elem group each
    int r  = idx >> 5;
    int k0 = (idx & 31) * 8;
    const float* src = (k0 < 128) ? (x + (size_t)r * HDIM + k0)
                                  : (h_prev + (size_t)r * HDIM + (k0 - 128));
    float4 v0 = *(const float4*)src;
    float4 v1 = *(const float4*)(src + 4);
    ushort4 p0, p1;
    p0.x = f2bf(v0.x); p0.y = f2bf(v0.y); p0.z = f2bf(v0.z); p0.w = f2bf(v0.w);
    p1.x = f2bf(v1.x); p1.y = f2bf(v1.y); p1.z = f2bf(v1.z); p1.w = f2bf(v1.w);
    unsigned short* dst = XH + (size_t)r * 256 + k0;
    *(ushort4*)dst = p0;
    *(ushort4*)(dst + 4) = p1;
}

__global__ __launch_bounds__(512, 4) void lstm_main(
    const unsigned short* __restrict__ XH,
    const float* __restrict__ c_prev,
    const unsigned short* __restrict__ Bp,
    const float* __restrict__ bi, const float* __restrict__ bf_,
    const float* __restrict__ bg, const float* __restrict__ bo,
    float* __restrict__ out)
{
    // 2 padded fp32 tiles (64 x 132) = 67584 B (epilogue transpose only).
    __shared__ float smem[2 * BM * LDT];
    float* hbuf = smem;
    float* cbuf = smem + BM * LDT;

    const int tid = threadIdx.x;
    const int m0 = blockIdx.x * BM;
    const int wave = tid >> 6;
    const int lane = tid & 63;
    const int t16 = lane & 15;
    const int q = lane >> 4;
    const int lane_off = t16 * 32 + q * 8;

    // ---- c_prev: coalesced float4 loads, park into cbuf (no barrier yet:
    // the only readers are epilogue lanes, gated by the post-GEMM barrier)
    float4 cpv[4];
    #pragma unroll
    for (int it = 0; it < 4; ++it) {
        int f = it * 512 + tid;
        int r = f >> 5, c4 = f & 31;
        cpv[it] = *(const float4*)(c_prev + (size_t)(m0 + r) * HDIM + c4 * 4);
    }
    #pragma unroll
    for (int it = 0; it < 4; ++it) {
        int f = it * 512 + tid;
        int r = f >> 5, c4 = f & 31;
        *(float4*)&cbuf[r * LDT + c4 * 4] = cpv[it];
    }

    // ---- GEMM: barrier-free. A direct from XH (L1-shared across waves),
    // B nontemporal from L2 (don't evict A from L1).
    const unsigned short* abase = XH + (size_t)(m0 + t16) * 256 + q * 8;
    const unsigned short* bbase = Bp + (size_t)(wave * 8) * 2048 + lane_off;

    f32x4 acc[4][4];
    const f32x4 zero = {0.0f, 0.0f, 0.0f, 0.0f};
    #pragma unroll
    for (int mi = 0; mi < 4; ++mi)
        #pragma unroll
        for (int ni = 0; ni < 4; ++ni)
            acc[mi][ni] = zero;

    #pragma unroll
    for (int kc = 0; kc < 8; ++kc) {
        s16x8 a[4], b[4];
        #pragma unroll
        for (int ni = 0; ni < 4; ++ni)
            b[ni] = __builtin_nontemporal_load((const s16x8*)(bbase + kc * 2048 + ni * 512));
        #pragma unroll
        for (int mi = 0; mi < 4; ++mi)
            a[mi] = *(const s16x8*)(abase + mi * 4096 + kc * 32);   // row m0+mi*16+t16, k=kc*32+q*8
        #pragma unroll
        for (int mi = 0; mi < 4; ++mi)
            #pragma unroll
            for (int ni = 0; ni < 4; ++ni)
                acc[mi][ni] = __builtin_amdgcn_mfma_f32_16x16x32_bf16(a[mi], b[ni], acc[mi][ni], 0, 0, 0);
    }
    __syncthreads();   // b1: all cbuf parks visible; GEMM used no LDS

    // ---- Epilogue in MFMA layout: cp from cbuf, compute, h/c back to LDS
    const int j = wave * 16 + t16;
    const float vbi = bi[j], vbf = bf_[j], vbg = bg[j], vbo = bo[j];

    #pragma unroll
    for (int mi = 0; mi < 4; ++mi) {
        #pragma unroll
        for (int r = 0; r < 4; ++r) {
            int rt = mi * 16 + q * 4 + r;          // row within tile
            float cp = cbuf[rt * LDT + j];
            float ig = fsigmoid(acc[mi][0][r] + vbi);
            float fg = fsigmoid(acc[mi][1][r] + vbf);
            float cc = ftanh(acc[mi][2][r] + vbg);
            float og = fsigmoid(acc[mi][3][r] + vbo);
            float c = fg * cp + ig * cc;
            float h = og * ftanh(c);
            hbuf[rt * LDT + j] = h;
            cbuf[rt * LDT + j] = c;                // own slot: read-before-write per lane
        }
    }
    __syncthreads();   // b2: h/c tiles complete

    // ---- Coalesced full-line float4 stores
    float* hout = out;
    float* cout = out + (size_t)B_ROWS * HDIM;
    #pragma unroll
    for (int it = 0; it < 4; ++it) {
        int f = it * 512 + tid;
        int r = f >> 5, c4 = f & 31;
        size_t goff = (size_t)(m0 + r) * HDIM + c4 * 4;
        *(float4*)(hout + goff) = *(const float4*)&hbuf[r * LDT + c4 * 4];
        *(float4*)(cout + goff) = *(const float4*)&cbuf[r * LDT + c4 * 4];
    }
}

extern "C" void kernel_launch(void* const* d_in, const int* in_sizes, int n_in,
                              void* d_out, int out_size, void* d_ws, size_t ws_size,
                              hipStream_t stream) {
    const float* x      = (const float*)d_in[0];
    const float* h_prev = (const float*)d_in[1];
    const float* c_prev = (const float*)d_in[2];
    const float* Wi = (const float*)d_in[3];
    const float* Ui = (const float*)d_in[4];
    const float* bi = (const float*)d_in[5];
    const float* Wf = (const float*)d_in[6];
    const float* Uf = (const float*)d_in[7];
    const float* bf = (const float*)d_in[8];
    const float* Wg = (const float*)d_in[9];
    const float* Ug = (const float*)d_in[10];
    const float* bg = (const float*)d_in[11];
    const float* Wo = (const float*)d_in[12];
    const float* Uo = (const float*)d_in[13];
    const float* bo = (const float*)d_in[14];

    // workspace: XH bf16 [131072][256] = 64 MiB, then Bp 256 KiB
    unsigned short* XH = (unsigned short*)d_ws;
    unsigned short* Bp = (unsigned short*)((char*)d_ws + (size_t)67108864);

    prep_weights<<<512, 256, 0, stream>>>(Wi, Ui, Wf, Uf, Wg, Ug, Wo, Uo, Bp);
    prep_xh<<<16384, 256, 0, stream>>>(x, h_prev, XH);
    lstm_main<<<B_ROWS / BM, 512, 0, stream>>>(XH, c_prev, Bp, bi, bf, bg, bo, (float*)d_out);
}

// Round 8
// 345.811 us; speedup vs baseline: 1.3160x; 1.3160x over previous
//
#include <hip/hip_runtime.h>

// LSTM cell, B=131072, IN=H=128, fp32 in/out.
// R10: swapped-operand GEMM. R9 proved A-frags must come from LDS (scattered
// global frag loads = 16x64B segments/instr, throughput death). R3/R5's cost
// is per-block serial machinery: 3 barriers + epilogue LDS transpose + c_prev
// LDS roundtrip. Swap MFMA roles: A = Bp weight frags (same bytes/addressing,
// L2-resident), B = staged activations (staging identical to R5). Then D-frag
// row=q*4+r -> j (4 consecutive j per lane), col=t16 -> m: epilogue reads
// c_prev as direct float4 [m][j..j+3], biases as float4 [j], stores h/c as
// direct float4. No transpose LDS, no c_prev parking, ONE barrier; waves
// retire independently. acc[gate4][mi2]=32 AGPR, BM=32, (512,4): unified ~96.
// Diagnostic: WRITE_SIZE >=220 MB => half-line store penalty (R2 signature).

#define B_ROWS 131072
#define HDIM 128
#define BM 32

typedef __attribute__((ext_vector_type(4))) float f32x4;
typedef __attribute__((ext_vector_type(8))) short s16x8;

__device__ inline unsigned short f2bf(float f) {
    unsigned int u = __float_as_uint(f);
    u += 0x7fffu + ((u >> 16) & 1u);   // RNE (inputs finite)
    return (unsigned short)(u >> 16);
}

__device__ inline float frcp(float x) { return __builtin_amdgcn_rcpf(x); }
__device__ inline float fsigmoid(float x) { return frcp(1.0f + __expf(-x)); }
__device__ inline float ftanh(float x) { return 1.0f - 2.0f * frcp(__expf(2.0f * x) + 1.0f); }

// Bp layout (ushort idx): (((w*8 + kc)*4 + ni)*512) + t16*32 + q*8 + e
// (w = j-tile 0..7, t16 = j within tile, ni = gate, k = kc*32+q*8+e)
__global__ void prep_weights(const float* __restrict__ Wi, const float* __restrict__ Ui,
                             const float* __restrict__ Wf, const float* __restrict__ Uf,
                             const float* __restrict__ Wg, const float* __restrict__ Ug,
                             const float* __restrict__ Wo, const float* __restrict__ Uo,
                             unsigned short* __restrict__ Bp) {
    int idx = blockIdx.x * 256 + threadIdx.x;   // 0..131071
    int e   = idx & 7;
    int q   = (idx >> 3) & 3;
    int t16 = (idx >> 5) & 15;
    int ni  = (idx >> 9) & 3;
    int kc  = (idx >> 11) & 7;
    int w   = idx >> 14;
    int j = w * 16 + t16;
    int k = kc * 32 + q * 8 + e;
    const float* Wp = ni == 0 ? Wi : ni == 1 ? Wf : ni == 2 ? Wg : Wo;
    const float* Up = ni == 0 ? Ui : ni == 1 ? Uf : ni == 2 ? Ug : Uo;
    float v = (k < 128) ? Wp[k * HDIM + j] : Up[(k - 128) * HDIM + j];
    Bp[idx] = f2bf(v);
}

__global__ __launch_bounds__(512, 4) void lstm_main(
    const float* __restrict__ x, const float* __restrict__ h_prev,
    const float* __restrict__ c_prev,
    const unsigned short* __restrict__ Bp,
    const float* __restrict__ bi, const float* __restrict__ bf_,
    const float* __restrict__ bg, const float* __restrict__ bo,
    float* __restrict__ out)
{
    // Only LDS: activation B-fragments, [mi(2)][kc(8)][t16=m(16)][q(4)][e(8)] = 16 KB
    __shared__ unsigned short Bs[8192];

    const int tid = threadIdx.x;
    const int m0 = blockIdx.x * BM;
    const int wave = tid >> 6;
    const int lane = tid & 63;
    const int t16 = lane & 15;
    const int q = lane >> 4;
    const int lane_off = t16 * 32 + q * 8;

    // ---- Stage activations (32 rows x 256 K) fp32 -> bf16 B-frag LDS layout
    #pragma unroll
    for (int it = 0; it < 4; ++it) {
        int fi = it * 512 + tid;               // 0..2047 float4s
        int r  = fi >> 6;                      // row 0..31
        int c4 = fi & 63;
        int k0 = c4 * 4;
        const float* src = (k0 < 128) ? (x + (size_t)(m0 + r) * HDIM + k0)
                                      : (h_prev + (size_t)(m0 + r) * HDIM + (k0 - 128));
        float4 v = *(const float4*)src;
        ushort4 p;
        p.x = f2bf(v.x); p.y = f2bf(v.y); p.z = f2bf(v.z); p.w = f2bf(v.w);
        int mi = r >> 4, t16r = r & 15;
        int kc = k0 >> 5, qq = (k0 >> 3) & 3, e0 = k0 & 7;
        *(ushort4*)&Bs[((mi * 8 + kc) * 16 + t16r) * 32 + qq * 8 + e0] = p;
    }
    __syncthreads();   // the only barrier

    // ---- GEMM: A = weight frags (wave w -> j-tile w, all 4 gates), B = Bs
    const unsigned short* abase = Bp + (size_t)wave * 16384 + lane_off;

    f32x4 acc[4][2];
    const f32x4 zero = {0.0f, 0.0f, 0.0f, 0.0f};
    #pragma unroll
    for (int g = 0; g < 4; ++g)
        #pragma unroll
        for (int mi = 0; mi < 2; ++mi)
            acc[g][mi] = zero;

    #pragma unroll
    for (int kc = 0; kc < 8; ++kc) {
        s16x8 b[2], a[4];
        #pragma unroll
        for (int mi = 0; mi < 2; ++mi)
            b[mi] = *(const s16x8*)&Bs[(mi * 8 + kc) * 512 + lane_off];
        #pragma unroll
        for (int g = 0; g < 4; ++g)
            a[g] = *(const s16x8*)(abase + kc * 2048 + g * 512);
        #pragma unroll
        for (int g = 0; g < 4; ++g)
            #pragma unroll
            for (int mi = 0; mi < 2; ++mi)
                acc[g][mi] = __builtin_amdgcn_mfma_f32_16x16x32_bf16(a[g], b[mi], acc[g][mi], 0, 0, 0);
    }

    // ---- Epilogue: lane holds j = wave*16 + q*4 + r (r=0..3), m = m0+mi*16+t16.
    // Direct float4 c_prev loads, float4 h/c stores. No barrier, no LDS.
    const int jv = wave * 16 + q * 4;
    const float4 vbi = *(const float4*)(bi + jv);
    const float4 vbf = *(const float4*)(bf_ + jv);
    const float4 vbg = *(const float4*)(bg + jv);
    const float4 vbo = *(const float4*)(bo + jv);

    float* hout = out;
    float* cout = out + (size_t)B_ROWS * HDIM;

    #pragma unroll
    for (int mi = 0; mi < 2; ++mi) {
        const size_t moff = (size_t)(m0 + mi * 16 + t16) * HDIM + jv;
        float4 cp = *(const float4*)(c_prev + moff);
        float4 hv, cv;
        #pragma unroll
        for (int r = 0; r < 4; ++r) {
            float bi_r = r == 0 ? vbi.x : r == 1 ? vbi.y : r == 2 ? vbi.z : vbi.w;
            float bf_r = r == 0 ? vbf.x : r == 1 ? vbf.y : r == 2 ? vbf.z : vbf.w;
            float bg_r = r == 0 ? vbg.x : r == 1 ? vbg.y : r == 2 ? vbg.z : vbg.w;
            float bo_r = r == 0 ? vbo.x : r == 1 ? vbo.y : r == 2 ? vbo.z : vbo.w;
            float cp_r = r == 0 ? cp.x : r == 1 ? cp.y : r == 2 ? cp.z : cp.w;
            float ig = fsigmoid(acc[0][mi][r] + bi_r);
            float fg = fsigmoid(acc[1][mi][r] + bf_r);
            float cc = ftanh(acc[2][mi][r] + bg_r);
            float og = fsigmoid(acc[3][mi][r] + bo_r);
            float c = fg * cp_r + ig * cc;
            float h = og * ftanh(c);
            if (r == 0) { hv.x = h; cv.x = c; }
            else if (r == 1) { hv.y = h; cv.y = c; }
            else if (r == 2) { hv.z = h; cv.z = c; }
            else { hv.w = h; cv.w = c; }
        }
        *(float4*)(hout + moff) = hv;
        *(float4*)(cout + moff) = cv;
    }
}

extern "C" void kernel_launch(void* const* d_in, const int* in_sizes, int n_in,
                              void* d_out, int out_size, void* d_ws, size_t ws_size,
                              hipStream_t stream) {
    const float* x      = (const float*)d_in[0];
    const float* h_prev = (const float*)d_in[1];
    const float* c_prev = (const float*)d_in[2];
    const float* Wi = (const float*)d_in[3];
    const float* Ui = (const float*)d_in[4];
    const float* bi = (const float*)d_in[5];
    const float* Wf = (const float*)d_in[6];
    const float* Uf = (const float*)d_in[7];
    const float* bf = (const float*)d_in[8];
    const float* Wg = (const float*)d_in[9];
    const float* Ug = (const float*)d_in[10];
    const float* bg = (const float*)d_in[11];
    const float* Wo = (const float*)d_in[12];
    const float* Uo = (const float*)d_in[13];
    const float* bo = (const float*)d_in[14];

    unsigned short* Bp = (unsigned short*)d_ws;   // 256 KB bf16 prepped weights

    prep_weights<<<512, 256, 0, stream>>>(Wi, Ui, Wf, Uf, Wg, Ug, Wo, Uo, Bp);
    lstm_main<<<B_ROWS / BM, 512, 0, stream>>>(x, h_prev, c_prev, Bp, bi, bf, bg, bo, (float*)d_out);
}